// Round 5
// baseline (258.218 us; speedup 1.0000x reference)
//
#include <hip/hip_runtime.h>

// Performer linear attention, MFMA bf16, split-K + reg-prefetch version.
// n=2, l=2048, h=8, e=64, m=2048. Dtype runtime-detected (bf16 confirmed R3/R4).
// ws layout (floats):
//   flag[16] | c_k[32768] | c_q[32768] | ksum01[2][32768] | kvf01[2][16][2048][64]
//   | oacc01[2][32768][64] | dacc01[2][32768]     total ~34.3 MB

#define LL 2048
#define HH 8
#define MM 2048
#define ROWSTR 512  // HH*64

#define NORMC 0.35355339059327373f   // 64^-0.25
#define RATIO 0.022097086912079608f  // 2048^-0.5
#define KEPS 1e-4f
#define REPS (RATIO * KEPS)
#define EPSD 1e-6f

#define KVSPLIT 2097152  // floats per kvf split
#define OSPLIT 2097152   // floats per oacc split
#define RSPLIT 32768     // floats per ksum/dacc split

typedef __attribute__((ext_vector_type(8))) short short8;
typedef __attribute__((ext_vector_type(4))) float f32x4;

#define MFMA(a, b, c) __builtin_amdgcn_mfma_f32_16x16x32_bf16((a), (b), (c), 0, 0, 0)

__device__ __forceinline__ unsigned short f2bf(float f) {  // RNE
    union { float f; unsigned int u; } v; v.f = f;
    unsigned int r = v.u + 0x7fffu + ((v.u >> 16) & 1u);
    return (unsigned short)(r >> 16);
}
__device__ __forceinline__ float bf2f(unsigned short u) {
    union { unsigned int ui; float f; } v; v.ui = ((unsigned int)u) << 16; return v.f;
}
__device__ __forceinline__ unsigned int pk2(float lo, float hi) {  // trunc pack
    return __builtin_amdgcn_perm(__float_as_uint(hi), __float_as_uint(lo), 0x07060302u);
}

// ---- 64x64 tile staging, split into load (global->reg) and store (reg->LDS) ----
template <bool BF16>
__device__ __forceinline__ void tile_load(const void* src, size_t base, size_t rstride,
                                          int t, uint4& A, uint4& B) {
    const int row = t >> 2, c16 = (t & 3) * 16;
    if (BF16) {
        const unsigned short* p = (const unsigned short*)src + base + (size_t)row * rstride + c16;
        A = *(const uint4*)p;
        B = *(const uint4*)(p + 8);
    } else {
        const float* p = (const float*)src + base + (size_t)row * rstride + c16;
        float4 f0 = ((const float4*)p)[0], f1 = ((const float4*)p)[1];
        float4 f2 = ((const float4*)p)[2], f3 = ((const float4*)p)[3];
        A.x = pk2(f0.x, f0.y); A.y = pk2(f0.z, f0.w);
        A.z = pk2(f1.x, f1.y); A.w = pk2(f1.z, f1.w);
        B.x = pk2(f2.x, f2.y); B.y = pk2(f2.z, f2.w);
        B.z = pk2(f3.x, f3.y); B.w = pk2(f3.z, f3.w);
    }
}
__device__ __forceinline__ void tile_store(unsigned short D[64][72], int t, uint4 A, uint4 B) {
    const int row = t >> 2, c16 = (t & 3) * 16;
    *(uint4*)&D[row][c16] = A;
    *(uint4*)&D[row][c16 + 8] = B;
}

// ---- V transpose staging: thread covers 2 s-rows x 8 e; b32 LDS writes (<=2-way) ----
template <bool BF16>
__device__ __forceinline__ void vt_load(const void* V, size_t base, int t, uint4& A, uint4& B) {
    const int s0 = (t & 31) * 2, e0 = (t >> 5) * 8;
    if (BF16) {
        const unsigned short* p = (const unsigned short*)V + base + (size_t)s0 * ROWSTR + e0;
        A = *(const uint4*)p;
        B = *(const uint4*)(p + ROWSTR);
    } else {
        const float* p = (const float*)V + base + (size_t)s0 * ROWSTR + e0;
        float4 f0 = ((const float4*)p)[0], f1 = ((const float4*)p)[1];
        const float* q = p + ROWSTR;
        float4 g0 = ((const float4*)q)[0], g1 = ((const float4*)q)[1];
        A.x = pk2(f0.x, f0.y); A.y = pk2(f0.z, f0.w);
        A.z = pk2(f1.x, f1.y); A.w = pk2(f1.z, f1.w);
        B.x = pk2(g0.x, g0.y); B.y = pk2(g0.z, g0.w);
        B.z = pk2(g1.x, g1.y); B.w = pk2(g1.z, g1.w);
    }
}
__device__ __forceinline__ void vt_store(unsigned short VT[64][72], int t, uint4 A, uint4 B) {
    const int s0 = (t & 31) * 2, e0 = (t >> 5) * 8;
    const unsigned ua[4] = {A.x, A.y, A.z, A.w}, ub[4] = {B.x, B.y, B.z, B.w};
    #pragma unroll
    for (int i = 0; i < 4; ++i) {
        *(unsigned*)&VT[e0 + 2 * i][s0] = (ua[i] & 0xFFFFu) | (ub[i] << 16);
        *(unsigned*)&VT[e0 + 2 * i + 1][s0] = (ua[i] >> 16) | (ub[i] & 0xFFFF0000u);
    }
}

// ---- kv pair staging for out: sum 2 f32 splits [nh][m][e], transpose to KVs[e][m] ----
__device__ __forceinline__ void kv2_load(const float* kvf01, size_t base, int t, float4 R[8]) {
    const int m0 = (t & 31) * 2, e0 = (t >> 5) * 8;
    const float* p = kvf01 + base + (size_t)m0 * 64 + e0;
    R[0] = ((const float4*)p)[0];        R[1] = ((const float4*)p)[1];
    R[2] = ((const float4*)(p + 64))[0]; R[3] = ((const float4*)(p + 64))[1];
    const float* q = p + KVSPLIT;
    R[4] = ((const float4*)q)[0];        R[5] = ((const float4*)q)[1];
    R[6] = ((const float4*)(q + 64))[0]; R[7] = ((const float4*)(q + 64))[1];
}
__device__ __forceinline__ void kv2_store(unsigned short D[64][72], int t, const float4 R[8]) {
    const int m0 = (t & 31) * 2, e0 = (t >> 5) * 8;
    const float r0[8] = {R[0].x + R[4].x, R[0].y + R[4].y, R[0].z + R[4].z, R[0].w + R[4].w,
                         R[1].x + R[5].x, R[1].y + R[5].y, R[1].z + R[5].z, R[1].w + R[5].w};
    const float r1[8] = {R[2].x + R[6].x, R[2].y + R[6].y, R[2].z + R[6].z, R[2].w + R[6].w,
                         R[3].x + R[7].x, R[3].y + R[7].y, R[3].z + R[7].z, R[3].w + R[7].w};
    #pragma unroll
    for (int i = 0; i < 8; ++i)
        *(unsigned*)&D[e0 + i][m0] = (unsigned)f2bf(r0[i]) | ((unsigned)f2bf(r1[i]) << 16);
}

// ---------------- dtype detection ----------------
__global__ void LinearAttention_15985868276494_detect(const unsigned short* __restrict__ P,
                                                      float* __restrict__ flag) {
    if (threadIdx.x == 0) {
        int sane = 1;
        #pragma unroll
        for (int i = 0; i < 16; ++i) {
            const unsigned e = (P[2 * i] >> 7) & 0xFF;
            if (e < 101 || e > 141) sane = 0;
        }
        *flag = sane ? 1.0f : 0.0f;
    }
}

// ---------------- stats: c[nh][l] ----------------
template <bool BF16>
__device__ void stats_impl(const void* X, const void* P, float* cws,
                           unsigned short Xs[64][72], unsigned short Ps[2][64][72],
                           float* diag_s) {
    const int t = threadIdx.x;
    const int w = t >> 6, ln = t & 15, quad = (t >> 4) & 3;
    const int row_base = blockIdx.x * 64;

    {
        uint4 xa, xb;
        tile_load<BF16>(X, (size_t)row_base * 64, 64, t, xa, xb);
        tile_store(Xs, t, xa, xb);
        uint4 pa, pb;
        tile_load<BF16>(P, 0, 64, t, pa, pb);
        tile_store(Ps[0], t, pa, pb);
    }
    __syncthreads();
    if (t < 64) {
        float s2 = 0.f;
        #pragma unroll
        for (int c = 0; c < 64; c += 8) {
            uint4 u = *(const uint4*)&Xs[t][c];
            const unsigned int ua[4] = {u.x, u.y, u.z, u.w};
            #pragma unroll
            for (int i = 0; i < 4; ++i) {
                float lo = bf2f((unsigned short)(ua[i] & 0xFFFF));
                float hi = bf2f((unsigned short)(ua[i] >> 16));
                s2 = fmaf(lo, lo, s2); s2 = fmaf(hi, hi, s2);
            }
        }
        diag_s[t] = s2;
    }
    const short8 xb0 = *(const short8*)&Xs[16 * w + ln][quad * 8];
    const short8 xb1 = *(const short8*)&Xs[16 * w + ln][32 + quad * 8];

    uint4 pfa, pfb;
    tile_load<BF16>(P, (size_t)64 * 64, 64, t, pfa, pfb);  // tile 1 prefetch

    float rmax = -3.0e38f;
    for (int mt = 0; mt < 32; ++mt) {
        const int cur = mt & 1;
        __syncthreads();
        if (mt + 1 < 32) {
            tile_store(Ps[cur ^ 1], t, pfa, pfb);
            if (mt + 2 < 32)
                tile_load<BF16>(P, (size_t)((mt + 2) * 64) * 64, 64, t, pfa, pfb);
        }
        #pragma unroll
        for (int ms = 0; ms < 4; ++ms) {
            f32x4 acc = {0.f, 0.f, 0.f, 0.f};
            acc = MFMA(*(const short8*)&Ps[cur][16 * ms + ln][quad * 8], xb0, acc);
            acc = MFMA(*(const short8*)&Ps[cur][16 * ms + ln][32 + quad * 8], xb1, acc);
            rmax = fmaxf(rmax, fmaxf(fmaxf(acc[0], acc[1]), fmaxf(acc[2], acc[3])));
        }
    }
    rmax = fmaxf(rmax, __shfl_xor(rmax, 16));
    rmax = fmaxf(rmax, __shfl_xor(rmax, 32));
    __syncthreads();
    if ((t & 63) < 16) {
        const int row = 16 * w + ln;
        const int rg = row_base + row;
        const int n = rg >> 14, l = (rg >> 3) & 2047, h = rg & 7;
        cws[(size_t)((n << 3) | h) * LL + l] =
            NORMC * rmax + (0.5f * NORMC * NORMC) * diag_s[row];
    }
}

__global__ __launch_bounds__(256) void LinearAttention_15985868276494_stats(
        const void* K, const void* Q, const void* P, const float* flag,
        float* c_k, float* c_q) {
    __shared__ unsigned short Xs[64][72];
    __shared__ unsigned short Ps[2][64][72];
    __shared__ float diag_s[64];
    const void* X = (blockIdx.y == 0) ? K : Q;
    float* cws = (blockIdx.y == 0) ? c_k : c_q;
    if (*flag != 0.f) stats_impl<true>(X, P, cws, Xs, Ps, diag_s);
    else stats_impl<false>(X, P, cws, Xs, Ps, diag_s);
}

// ---------------- kv (split-s): kvfp[nh][m][e] f32 partial, ksump[nh][m] ----------------
template <bool BF16>
__device__ void kv_impl(const void* K, const void* V, const void* P, const float* cws,
                        float* kvf01, float* ksum01,
                        unsigned short Ks[64][72], unsigned short Ps[64][72],
                        unsigned short VT[64][72], unsigned short FT[64][72], float* cks) {
    const int t = threadIdx.x;
    const int w = t >> 6, ln = t & 15, quad = (t >> 4) & 3;
    const int mt = blockIdx.x, nh = blockIdx.y, sp = blockIdx.z;
    const int n = nh >> 3, h = nh & 7;
    const size_t xbase = (size_t)n * (LL * ROWSTR) + (size_t)h * 64;

    {
        uint4 pa, pb;
        tile_load<BF16>(P, (size_t)(mt * 64) * 64, 64, t, pa, pb);
        tile_store(Ps, t, pa, pb);
    }
    f32x4 akv[4] = {{0.f, 0.f, 0.f, 0.f}, {0.f, 0.f, 0.f, 0.f},
                    {0.f, 0.f, 0.f, 0.f}, {0.f, 0.f, 0.f, 0.f}};
    f32x4 aks = {0.f, 0.f, 0.f, 0.f};
    const short8 ones = {0x3F80, 0x3F80, 0x3F80, 0x3F80, 0x3F80, 0x3F80, 0x3F80, 0x3F80};

    const int st0 = sp * 16;
    uint4 kA, kB, vA, vB;
    float ckr = 0.f;
    tile_load<BF16>(K, xbase + (size_t)(st0 * 64) * ROWSTR, ROWSTR, t, kA, kB);
    vt_load<BF16>(V, xbase + (size_t)(st0 * 64) * ROWSTR, t, vA, vB);
    if (t < 64) ckr = cws[(size_t)nh * LL + st0 * 64 + t];
    __syncthreads();  // Ps visible
    const short8 pb0 = *(const short8*)&Ps[16 * w + ln][quad * 8];
    const short8 pb1 = *(const short8*)&Ps[16 * w + ln][32 + quad * 8];

    for (int i = 0; i < 16; ++i) {
        const int st = st0 + i;
        __syncthreads();  // (A) prev gemm2 reads of VT/FT done
        tile_store(Ks, t, kA, kB);
        vt_store(VT, t, vA, vB);
        if (t < 64) cks[t] = ckr;
        if (i + 1 < 16) {
            tile_load<BF16>(K, xbase + (size_t)((st + 1) * 64) * ROWSTR, ROWSTR, t, kA, kB);
            vt_load<BF16>(V, xbase + (size_t)((st + 1) * 64) * ROWSTR, t, vA, vB);
            if (t < 64) ckr = cws[(size_t)nh * LL + (st + 1) * 64 + t];
        }
        __syncthreads();  // (B) staging visible
        #pragma unroll
        for (int ss = 0; ss < 4; ++ss) {
            f32x4 acc = {0.f, 0.f, 0.f, 0.f};
            acc = MFMA(*(const short8*)&Ks[16 * ss + ln][quad * 8], pb0, acc);
            acc = MFMA(*(const short8*)&Ks[16 * ss + ln][32 + quad * 8], pb1, acc);
            const float4 c4 = *(const float4*)&cks[16 * ss + 4 * quad];
            const float ca[4] = {c4.x, c4.y, c4.z, c4.w};
            float f[4];
            #pragma unroll
            for (int j = 0; j < 4; ++j) {
                const float arg = fminf(fmaf(acc[j], NORMC, -ca[j]), 0.f);
                f[j] = fmaf(__expf(arg), RATIO, REPS);
            }
            uint2 o; o.x = pk2(f[0], f[1]); o.y = pk2(f[2], f[3]);
            *(uint2*)&FT[16 * w + ln][16 * ss + 4 * quad] = o;  // FT[m][s]
        }
        __syncthreads();  // (C) FT visible
        #pragma unroll
        for (int k = 0; k < 2; ++k) {
            const short8 af = *(const short8*)&FT[16 * w + ln][32 * k + quad * 8];
            aks = MFMA(af, ones, aks);
            #pragma unroll
            for (int es = 0; es < 4; ++es)
                akv[es] = MFMA(af, *(const short8*)&VT[16 * es + ln][32 * k + quad * 8], akv[es]);
        }
    }
    // epilogue: kvfp[nh][m][e] — lanes ln cover 16 contiguous e (full 64B sectors)
    float* kvfp = kvf01 + (size_t)sp * KVSPLIT + (size_t)nh * (MM * 64);
    #pragma unroll
    for (int r = 0; r < 4; ++r) {
        const int m = mt * 64 + 16 * w + 4 * quad + r;
        #pragma unroll
        for (int es = 0; es < 4; ++es)
            kvfp[(size_t)m * 64 + 16 * es + ln] = akv[es][r];
        if (ln == 0)
            ksum01[(size_t)sp * RSPLIT + (size_t)nh * MM + m] = aks[r];
    }
}

__global__ __launch_bounds__(256) void LinearAttention_15985868276494_kv(
        const void* K, const void* V, const void* P, const float* flag,
        const float* cws, float* kvf01, float* ksum01) {
    __shared__ unsigned short Ks[64][72];
    __shared__ unsigned short Ps[64][72];
    __shared__ unsigned short VT[64][72];
    __shared__ unsigned short FT[64][72];
    __shared__ float cks[64];
    if (*flag != 0.f) kv_impl<true>(K, V, P, cws, kvf01, ksum01, Ks, Ps, VT, FT, cks);
    else kv_impl<false>(K, V, P, cws, kvf01, ksum01, Ks, Ps, VT, FT, cks);
}

// ---------------- out (split-m): oaccp[nlh][e] f32 partial, daccp[nlh] ----------------
template <bool BF16>
__device__ void out_impl(const void* Q, const void* P, const float* cqw,
                         const float* kvf01, const float* ksum01,
                         float* oacc01, float* dacc01,
                         unsigned short Qs[64][72], unsigned short Ps[64][72],
                         unsigned short KVs[64][72], unsigned short Fs[64][72],
                         unsigned short* kss) {
    const int t = threadIdx.x;
    const int w = t >> 6, ln = t & 15, quad = (t >> 4) & 3;
    const int lb = blockIdx.x, nh = blockIdx.y, mp = blockIdx.z;
    const int n = nh >> 3, h = nh & 7;
    const size_t qbase = (size_t)n * (LL * ROWSTR) + (size_t)h * 64 + (size_t)(lb * 64) * ROWSTR;
    const size_t kvbase = (size_t)nh * (MM * 64);

    {
        uint4 qa, qb;
        tile_load<BF16>(Q, qbase, ROWSTR, t, qa, qb);
        tile_store(Qs, t, qa, qb);
    }
    const float cq = cqw[(size_t)nh * LL + lb * 64 + 16 * w + ln];

    f32x4 ao[4] = {{0.f, 0.f, 0.f, 0.f}, {0.f, 0.f, 0.f, 0.f},
                   {0.f, 0.f, 0.f, 0.f}, {0.f, 0.f, 0.f, 0.f}};
    f32x4 ad = {0.f, 0.f, 0.f, 0.f};

    const int mt0 = mp * 16;
    uint4 pA, pB; float4 kvR[8]; float ksr = 0.f;
    tile_load<BF16>(P, (size_t)(mt0 * 64) * 64, 64, t, pA, pB);
    kv2_load(kvf01, kvbase + (size_t)(mt0 * 64) * 64, t, kvR);
    if (t < 64) ksr = ksum01[(size_t)nh * MM + mt0 * 64 + t] +
                      ksum01[RSPLIT + (size_t)nh * MM + mt0 * 64 + t];
    __syncthreads();  // Qs visible
    const short8 qb0 = *(const short8*)&Qs[16 * w + ln][quad * 8];
    const short8 qb1 = *(const short8*)&Qs[16 * w + ln][32 + quad * 8];

    for (int i = 0; i < 16; ++i) {
        const int mt = mt0 + i;
        __syncthreads();  // (A)
        tile_store(Ps, t, pA, pB);
        kv2_store(KVs, t, kvR);
        if (t < 64) kss[t] = f2bf(ksr);
        if (i + 1 < 16) {
            tile_load<BF16>(P, (size_t)((mt + 1) * 64) * 64, 64, t, pA, pB);
            kv2_load(kvf01, kvbase + (size_t)((mt + 1) * 64) * 64, t, kvR);
            if (t < 64) ksr = ksum01[(size_t)nh * MM + (mt + 1) * 64 + t] +
                              ksum01[RSPLIT + (size_t)nh * MM + (mt + 1) * 64 + t];
        }
        __syncthreads();  // (B)
        #pragma unroll
        for (int ms = 0; ms < 4; ++ms) {
            f32x4 acc = {0.f, 0.f, 0.f, 0.f};
            acc = MFMA(*(const short8*)&Ps[16 * ms + ln][quad * 8], qb0, acc);
            acc = MFMA(*(const short8*)&Ps[16 * ms + ln][32 + quad * 8], qb1, acc);
            float f[4];
            #pragma unroll
            for (int j = 0; j < 4; ++j) {
                const float arg = fminf(fmaf(acc[j], NORMC, -cq), 0.f);
                f[j] = fmaf(__expf(arg), RATIO, REPS);
            }
            uint2 o; o.x = pk2(f[0], f[1]); o.y = pk2(f[2], f[3]);
            *(uint2*)&Fs[16 * w + ln][16 * ms + 4 * quad] = o;  // Fs[l][m]
        }
        __syncthreads();  // (C)
        #pragma unroll
        for (int k = 0; k < 2; ++k) {
            const short8 af = *(const short8*)&Fs[16 * w + ln][32 * k + quad * 8];
            const short8 bs = *(const short8*)&kss[32 * k + quad * 8];
            ad = MFMA(af, bs, ad);
            #pragma unroll
            for (int es = 0; es < 4; ++es)
                ao[es] = MFMA(af, *(const short8*)&KVs[16 * es + ln][32 * k + quad * 8], ao[es]);
        }
    }
    float* oaccp = oacc01 + (size_t)mp * OSPLIT;
    float* daccp = dacc01 + (size_t)mp * RSPLIT;
    #pragma unroll
    for (int r = 0; r < 4; ++r) {
        const int l = lb * 64 + 16 * w + 4 * quad + r;
        const size_t rowi = (size_t)(n * LL + l) * HH + h;
        #pragma unroll
        for (int es = 0; es < 4; ++es)
            oaccp[rowi * 64 + 16 * es + ln] = ao[es][r];
        if (ln == 0) daccp[rowi] = ad[r];
    }
}

__global__ __launch_bounds__(256) void LinearAttention_15985868276494_out(
        const void* Q, const void* P, const float* flag, const float* cqw,
        const float* kvf01, const float* ksum01, float* oacc01, float* dacc01) {
    __shared__ unsigned short Qs[64][72];
    __shared__ unsigned short Ps[64][72];
    __shared__ unsigned short KVs[64][72];
    __shared__ unsigned short Fs[64][72];
    __shared__ unsigned short kss[72];
    if (*flag != 0.f)
        out_impl<true>(Q, P, cqw, kvf01, ksum01, oacc01, dacc01, Qs, Ps, KVs, Fs, kss);
    else
        out_impl<false>(Q, P, cqw, kvf01, ksum01, oacc01, dacc01, Qs, Ps, KVs, Fs, kss);
}

// ---------------- final: sum partials, apply z, write output ----------------
__global__ __launch_bounds__(256) void LinearAttention_15985868276494_final(
        const float* __restrict__ oacc01, const float* __restrict__ dacc01,
        const float* __restrict__ flag, void* __restrict__ out) {
    const int gid = blockIdx.x * 256 + threadIdx.x;  // 524288 total
    const size_t i4 = (size_t)gid * 4;
    const int row = gid >> 4;
    const float d = dacc01[row] + dacc01[RSPLIT + row];
    const float z = 1.0f / (d + EPSD);
    const float4 a = *(const float4*)&oacc01[i4];
    const float4 b = *(const float4*)&oacc01[OSPLIT + i4];
    const float4 o = make_float4((a.x + b.x) * z, (a.y + b.y) * z,
                                 (a.z + b.z) * z, (a.w + b.w) * z);
    if (*flag != 0.f) {
        ushort4 u;
        u.x = f2bf(o.x); u.y = f2bf(o.y); u.z = f2bf(o.z); u.w = f2bf(o.w);
        *(ushort4*)((unsigned short*)out + i4) = u;
    } else {
        *(float4*)((float*)out + i4) = o;
    }
}

extern "C" void kernel_launch(void* const* d_in, const int* in_sizes, int n_in,
                              void* d_out, int out_size, void* d_ws, size_t ws_size,
                              hipStream_t stream) {
    const void* Q = d_in[0];
    const void* K = d_in[1];
    const void* V = d_in[2];
    const void* P = d_in[3];

    float* W = (float*)d_ws;
    float* flag = W;                                  // [16]
    float* c_k = W + 16;                              // [32768]
    float* c_q = c_k + 32768;                         // [32768]
    float* ksum01 = c_q + 32768;                      // [2][32768]
    float* kvf01 = ksum01 + 2 * RSPLIT;               // [2][16][2048][64]
    float* oacc01 = kvf01 + 2 * KVSPLIT;              // [2][32768][64]
    float* dacc01 = oacc01 + 2 * OSPLIT;              // [2][32768]

    LinearAttention_15985868276494_detect<<<1, 64, 0, stream>>>(
        (const unsigned short*)P, flag);
    LinearAttention_15985868276494_stats<<<dim3(512, 2), 256, 0, stream>>>(
        K, Q, P, flag, c_k, c_q);
    LinearAttention_15985868276494_kv<<<dim3(32, 16, 2), 256, 0, stream>>>(
        K, V, P, flag, c_k, kvf01, ksum01);
    LinearAttention_15985868276494_out<<<dim3(32, 16, 2), 256, 0, stream>>>(
        Q, P, flag, c_q, kvf01, ksum01, oacc01, dacc01);
    LinearAttention_15985868276494_final<<<2048, 256, 0, stream>>>(
        oacc01, dacc01, flag, d_out);
}

// Round 6
// 214.559 us; speedup vs baseline: 1.2035x; 1.2035x over previous
//
#include <hip/hip_runtime.h>

// Performer linear attention, MFMA bf16, 1-barrier/iter double-buffered version.
// n=2, l=2048, h=8, e=64, m=2048. Dtype runtime-detected (bf16 confirmed R3-R5).
// ws (floats): flag[16] | c_k[32768] | c_q[32768] | ksum01[2][32768]
//   | kvf01[2][16][2048][64] f32 | ksum[32768] | kvT bf16[16][64][2048]  ~22 MB

#define LL 2048
#define HH 8
#define MM 2048
#define ROWSTR 512  // HH*64

#define NORMC 0.35355339059327373f   // 64^-0.25
#define RATIO 0.022097086912079608f  // 2048^-0.5
#define KEPS 1e-4f
#define REPS (RATIO * KEPS)
#define EPSD 1e-6f

#define KVSPLIT 2097152  // floats per kvf split
#define RSPLIT 32768     // floats per ksum split

typedef __attribute__((ext_vector_type(8))) short short8;
typedef __attribute__((ext_vector_type(4))) float f32x4;

#define MFMA(a, b, c) __builtin_amdgcn_mfma_f32_16x16x32_bf16((a), (b), (c), 0, 0, 0)

__device__ __forceinline__ unsigned short f2bf(float f) {  // RNE
    union { float f; unsigned int u; } v; v.f = f;
    unsigned int r = v.u + 0x7fffu + ((v.u >> 16) & 1u);
    return (unsigned short)(r >> 16);
}
__device__ __forceinline__ float bf2f(unsigned short u) {
    union { unsigned int ui; float f; } v; v.ui = ((unsigned int)u) << 16; return v.f;
}
__device__ __forceinline__ unsigned int pk2(float lo, float hi) {  // trunc pack
    return __builtin_amdgcn_perm(__float_as_uint(hi), __float_as_uint(lo), 0x07060302u);
}

// ---- 64x64 tile staging: load (global->reg) and store (reg->LDS) ----
template <bool BF16>
__device__ __forceinline__ void tile_load(const void* src, size_t base, size_t rstride,
                                          int t, uint4& A, uint4& B) {
    const int row = t >> 2, c16 = (t & 3) * 16;
    if (BF16) {
        const unsigned short* p = (const unsigned short*)src + base + (size_t)row * rstride + c16;
        A = *(const uint4*)p;
        B = *(const uint4*)(p + 8);
    } else {
        const float* p = (const float*)src + base + (size_t)row * rstride + c16;
        float4 f0 = ((const float4*)p)[0], f1 = ((const float4*)p)[1];
        float4 f2 = ((const float4*)p)[2], f3 = ((const float4*)p)[3];
        A.x = pk2(f0.x, f0.y); A.y = pk2(f0.z, f0.w);
        A.z = pk2(f1.x, f1.y); A.w = pk2(f1.z, f1.w);
        B.x = pk2(f2.x, f2.y); B.y = pk2(f2.z, f2.w);
        B.z = pk2(f3.x, f3.y); B.w = pk2(f3.z, f3.w);
    }
}
__device__ __forceinline__ void tile_store(unsigned short D[64][72], int t, uint4 A, uint4 B) {
    const int row = t >> 2, c16 = (t & 3) * 16;
    *(uint4*)&D[row][c16] = A;
    *(uint4*)&D[row][c16 + 8] = B;
}

// ---- V transpose staging: 2 s-rows x 8 e per thread; b32 LDS writes (<=2-way) ----
template <bool BF16>
__device__ __forceinline__ void vt_load(const void* V, size_t base, int t, uint4& A, uint4& B) {
    const int s0 = (t & 31) * 2, e0 = (t >> 5) * 8;
    if (BF16) {
        const unsigned short* p = (const unsigned short*)V + base + (size_t)s0 * ROWSTR + e0;
        A = *(const uint4*)p;
        B = *(const uint4*)(p + ROWSTR);
    } else {
        const float* p = (const float*)V + base + (size_t)s0 * ROWSTR + e0;
        float4 f0 = ((const float4*)p)[0], f1 = ((const float4*)p)[1];
        const float* q = p + ROWSTR;
        float4 g0 = ((const float4*)q)[0], g1 = ((const float4*)q)[1];
        A.x = pk2(f0.x, f0.y); A.y = pk2(f0.z, f0.w);
        A.z = pk2(f1.x, f1.y); A.w = pk2(f1.z, f1.w);
        B.x = pk2(g0.x, g0.y); B.y = pk2(g0.z, g0.w);
        B.z = pk2(g1.x, g1.y); B.w = pk2(g1.z, g1.w);
    }
}
__device__ __forceinline__ void vt_store(unsigned short VT[64][72], int t, uint4 A, uint4 B) {
    const int s0 = (t & 31) * 2, e0 = (t >> 5) * 8;
    const unsigned ua[4] = {A.x, A.y, A.z, A.w}, ub[4] = {B.x, B.y, B.z, B.w};
    #pragma unroll
    for (int i = 0; i < 4; ++i) {
        *(unsigned*)&VT[e0 + 2 * i][s0] = (ua[i] & 0xFFFFu) | (ub[i] << 16);
        *(unsigned*)&VT[e0 + 2 * i + 1][s0] = (ua[i] >> 16) | (ub[i] & 0xFFFF0000u);
    }
}

// ---- kv split-pair load + transpose-store (used by reduce kernel) ----
__device__ __forceinline__ void kv2_load(const float* kvf01, size_t base, int t, float4 R[8]) {
    const int m0 = (t & 31) * 2, e0 = (t >> 5) * 8;
    const float* p = kvf01 + base + (size_t)m0 * 64 + e0;
    R[0] = ((const float4*)p)[0];        R[1] = ((const float4*)p)[1];
    R[2] = ((const float4*)(p + 64))[0]; R[3] = ((const float4*)(p + 64))[1];
    const float* q = p + KVSPLIT;
    R[4] = ((const float4*)q)[0];        R[5] = ((const float4*)q)[1];
    R[6] = ((const float4*)(q + 64))[0]; R[7] = ((const float4*)(q + 64))[1];
}
__device__ __forceinline__ void kv2_store(unsigned short D[64][72], int t, const float4 R[8]) {
    const int m0 = (t & 31) * 2, e0 = (t >> 5) * 8;
    const float r0[8] = {R[0].x + R[4].x, R[0].y + R[4].y, R[0].z + R[4].z, R[0].w + R[4].w,
                         R[1].x + R[5].x, R[1].y + R[5].y, R[1].z + R[5].z, R[1].w + R[5].w};
    const float r1[8] = {R[2].x + R[6].x, R[2].y + R[6].y, R[2].z + R[6].z, R[2].w + R[6].w,
                         R[3].x + R[7].x, R[3].y + R[7].y, R[3].z + R[7].z, R[3].w + R[7].w};
    #pragma unroll
    for (int i = 0; i < 8; ++i)
        *(unsigned*)&D[e0 + i][m0] = (unsigned)f2bf(r0[i]) | ((unsigned)f2bf(r1[i]) << 16);
}

// ---------------- dtype detection ----------------
__global__ void LinearAttention_15985868276494_detect(const unsigned short* __restrict__ P,
                                                      float* __restrict__ flag) {
    if (threadIdx.x == 0) {
        int sane = 1;
        #pragma unroll
        for (int i = 0; i < 16; ++i) {
            const unsigned e = (P[2 * i] >> 7) & 0xFF;
            if (e < 101 || e > 141) sane = 0;
        }
        *flag = sane ? 1.0f : 0.0f;
    }
}

// ---------------- stats: c[nh][l] ----------------
template <bool BF16>
__device__ void stats_impl(const void* X, const void* P, float* cws,
                           unsigned short Xs[64][72], unsigned short Ps[2][64][72],
                           float* diag_s) {
    const int t = threadIdx.x;
    const int w = t >> 6, ln = t & 15, quad = (t >> 4) & 3;
    const int row_base = blockIdx.x * 64;

    {
        uint4 xa, xb;
        tile_load<BF16>(X, (size_t)row_base * 64, 64, t, xa, xb);
        tile_store(Xs, t, xa, xb);
        uint4 pa, pb;
        tile_load<BF16>(P, 0, 64, t, pa, pb);
        tile_store(Ps[0], t, pa, pb);
    }
    __syncthreads();
    if (t < 64) {
        float s2 = 0.f;
        #pragma unroll
        for (int c = 0; c < 64; c += 8) {
            uint4 u = *(const uint4*)&Xs[t][c];
            const unsigned int ua[4] = {u.x, u.y, u.z, u.w};
            #pragma unroll
            for (int i = 0; i < 4; ++i) {
                float lo = bf2f((unsigned short)(ua[i] & 0xFFFF));
                float hi = bf2f((unsigned short)(ua[i] >> 16));
                s2 = fmaf(lo, lo, s2); s2 = fmaf(hi, hi, s2);
            }
        }
        diag_s[t] = s2;
    }
    const short8 xb0 = *(const short8*)&Xs[16 * w + ln][quad * 8];
    const short8 xb1 = *(const short8*)&Xs[16 * w + ln][32 + quad * 8];

    uint4 pfa, pfb;
    tile_load<BF16>(P, (size_t)64 * 64, 64, t, pfa, pfb);

    float rmax = -3.0e38f;
    for (int mt = 0; mt < 32; ++mt) {
        const int cur = mt & 1;
        __syncthreads();
        if (mt + 1 < 32) {
            tile_store(Ps[cur ^ 1], t, pfa, pfb);
            if (mt + 2 < 32)
                tile_load<BF16>(P, (size_t)((mt + 2) * 64) * 64, 64, t, pfa, pfb);
        }
        #pragma unroll
        for (int ms = 0; ms < 4; ++ms) {
            f32x4 acc = {0.f, 0.f, 0.f, 0.f};
            acc = MFMA(*(const short8*)&Ps[cur][16 * ms + ln][quad * 8], xb0, acc);
            acc = MFMA(*(const short8*)&Ps[cur][16 * ms + ln][32 + quad * 8], xb1, acc);
            rmax = fmaxf(rmax, fmaxf(fmaxf(acc[0], acc[1]), fmaxf(acc[2], acc[3])));
        }
    }
    rmax = fmaxf(rmax, __shfl_xor(rmax, 16));
    rmax = fmaxf(rmax, __shfl_xor(rmax, 32));
    __syncthreads();
    if ((t & 63) < 16) {
        const int row = 16 * w + ln;
        const int rg = row_base + row;
        const int n = rg >> 14, l = (rg >> 3) & 2047, h = rg & 7;
        cws[(size_t)((n << 3) | h) * LL + l] =
            NORMC * rmax + (0.5f * NORMC * NORMC) * diag_s[row];
    }
}

__global__ __launch_bounds__(256) void LinearAttention_15985868276494_stats(
        const void* K, const void* Q, const void* P, const float* flag,
        float* c_k, float* c_q) {
    __shared__ unsigned short Xs[64][72];
    __shared__ unsigned short Ps[2][64][72];
    __shared__ float diag_s[64];
    const void* X = (blockIdx.y == 0) ? K : Q;
    float* cws = (blockIdx.y == 0) ? c_k : c_q;
    if (*flag != 0.f) stats_impl<true>(X, P, cws, Xs, Ps, diag_s);
    else stats_impl<false>(X, P, cws, Xs, Ps, diag_s);
}

// ---------------- kv (split-s, 1 barrier/iter): kvfp[nh][m][e] f32, ksump ----------------
template <bool BF16>
__device__ void kv_impl(const void* K, const void* V, const void* P, const float* cws,
                        float* kvf01, float* ksum01,
                        unsigned short Ks[2][64][72], unsigned short VT[2][64][72],
                        unsigned short Ps[64][72], unsigned short FT[64][72],
                        float cks[2][64]) {
    const int t = threadIdx.x;
    const int w = t >> 6, ln = t & 15, quad = (t >> 4) & 3;
    const int mt = blockIdx.x, nh = blockIdx.y, sp = blockIdx.z;
    const int n = nh >> 3, h = nh & 7;
    const size_t xbase = (size_t)n * (LL * ROWSTR) + (size_t)h * 64;
    const int st0 = sp * 16;

    {
        uint4 pa, pb;
        tile_load<BF16>(P, (size_t)(mt * 64) * 64, 64, t, pa, pb);
        tile_store(Ps, t, pa, pb);
    }
    uint4 kA, kB, vA, vB;
    float ckr = 0.f;
    // iter 0 -> buf 0
    tile_load<BF16>(K, xbase + (size_t)(st0 * 64) * ROWSTR, ROWSTR, t, kA, kB);
    vt_load<BF16>(V, xbase + (size_t)(st0 * 64) * ROWSTR, t, vA, vB);
    if (t < 64) ckr = cws[(size_t)nh * LL + st0 * 64 + t];
    tile_store(Ks[0], t, kA, kB);
    vt_store(VT[0], t, vA, vB);
    if (t < 64) cks[0][t] = ckr;
    // prefetch iter 1
    tile_load<BF16>(K, xbase + (size_t)((st0 + 1) * 64) * ROWSTR, ROWSTR, t, kA, kB);
    vt_load<BF16>(V, xbase + (size_t)((st0 + 1) * 64) * ROWSTR, t, vA, vB);
    if (t < 64) ckr = cws[(size_t)nh * LL + (st0 + 1) * 64 + t];
    __syncthreads();

    const short8 pb0 = *(const short8*)&Ps[16 * w + ln][quad * 8];
    const short8 pb1 = *(const short8*)&Ps[16 * w + ln][32 + quad * 8];
    f32x4 akv[4] = {{0.f, 0.f, 0.f, 0.f}, {0.f, 0.f, 0.f, 0.f},
                    {0.f, 0.f, 0.f, 0.f}, {0.f, 0.f, 0.f, 0.f}};
    f32x4 aks = {0.f, 0.f, 0.f, 0.f};
    const short8 ones = {0x3F80, 0x3F80, 0x3F80, 0x3F80, 0x3F80, 0x3F80, 0x3F80, 0x3F80};

    for (int i = 0; i < 16; ++i) {
        const int cur = i & 1;
        if (i + 1 < 16) {
            tile_store(Ks[cur ^ 1], t, kA, kB);
            vt_store(VT[cur ^ 1], t, vA, vB);
            if (t < 64) cks[cur ^ 1][t] = ckr;
            if (i + 2 < 16) {
                const int st = st0 + i + 2;
                tile_load<BF16>(K, xbase + (size_t)(st * 64) * ROWSTR, ROWSTR, t, kA, kB);
                vt_load<BF16>(V, xbase + (size_t)(st * 64) * ROWSTR, t, vA, vB);
                if (t < 64) ckr = cws[(size_t)nh * LL + st * 64 + t];
            }
        }
        // gemm1 -> FT (wave-local rows: no barrier needed before gemm2)
        #pragma unroll
        for (int ss = 0; ss < 4; ++ss) {
            f32x4 acc = {0.f, 0.f, 0.f, 0.f};
            acc = MFMA(*(const short8*)&Ks[cur][16 * ss + ln][quad * 8], pb0, acc);
            acc = MFMA(*(const short8*)&Ks[cur][16 * ss + ln][32 + quad * 8], pb1, acc);
            const float4 c4 = *(const float4*)&cks[cur][16 * ss + 4 * quad];
            const float ca[4] = {c4.x, c4.y, c4.z, c4.w};
            float f[4];
            #pragma unroll
            for (int j = 0; j < 4; ++j) {
                const float arg = fminf(fmaf(acc[j], NORMC, -ca[j]), 0.f);
                f[j] = fmaf(__expf(arg), RATIO, REPS);
            }
            uint2 o; o.x = pk2(f[0], f[1]); o.y = pk2(f[2], f[3]);
            *(uint2*)&FT[16 * w + ln][16 * ss + 4 * quad] = o;  // FT[m][s]
        }
        // gemm2 (reads FT rows this wave just wrote + VT[cur])
        #pragma unroll
        for (int k = 0; k < 2; ++k) {
            const short8 af = *(const short8*)&FT[16 * w + ln][32 * k + quad * 8];
            aks = MFMA(af, ones, aks);
            #pragma unroll
            for (int es = 0; es < 4; ++es)
                akv[es] = MFMA(af, *(const short8*)&VT[cur][16 * es + ln][32 * k + quad * 8],
                               akv[es]);
        }
        __syncthreads();
    }
    float* kvfp = kvf01 + (size_t)sp * KVSPLIT + (size_t)nh * (MM * 64);
    #pragma unroll
    for (int r = 0; r < 4; ++r) {
        const int m = mt * 64 + 16 * w + 4 * quad + r;
        #pragma unroll
        for (int es = 0; es < 4; ++es)
            kvfp[(size_t)m * 64 + 16 * es + ln] = akv[es][r];
        if (ln == 0)
            ksum01[(size_t)sp * RSPLIT + (size_t)nh * MM + m] = aks[r];
    }
}

__global__ __launch_bounds__(256) void LinearAttention_15985868276494_kv(
        const void* K, const void* V, const void* P, const float* flag,
        const float* cws, float* kvf01, float* ksum01) {
    __shared__ unsigned short Ks[2][64][72];
    __shared__ unsigned short VT[2][64][72];
    __shared__ unsigned short Ps[64][72];
    __shared__ unsigned short FT[64][72];
    __shared__ float cks[2][64];
    if (*flag != 0.f) kv_impl<true>(K, V, P, cws, kvf01, ksum01, Ks, VT, Ps, FT, cks);
    else kv_impl<false>(K, V, P, cws, kvf01, ksum01, Ks, VT, Ps, FT, cks);
}

// ---------------- reduce: kvT[nh][e][m] bf16 = sum of splits; ksum summed ----------------
__global__ __launch_bounds__(256) void LinearAttention_15985868276494_reduce(
        const float* __restrict__ kvf01, const float* __restrict__ ksum01,
        unsigned short* __restrict__ kvT, float* __restrict__ ksum) {
    __shared__ unsigned short T[64][72];
    const int t = threadIdx.x;
    const int mt = blockIdx.x, nh = blockIdx.y;
    float4 R[8];
    kv2_load(kvf01, (size_t)nh * (MM * 64) + (size_t)(mt * 64) * 64, t, R);
    kv2_store(T, t, R);
    if (t < 64)
        ksum[(size_t)nh * MM + mt * 64 + t] =
            ksum01[(size_t)nh * MM + mt * 64 + t] +
            ksum01[RSPLIT + (size_t)nh * MM + mt * 64 + t];
    __syncthreads();
    const int e = t >> 2, c = (t & 3) * 16;
    uint4 a = *(const uint4*)&T[e][c];
    uint4 b = *(const uint4*)&T[e][c + 8];
    unsigned short* dst = kvT + ((size_t)nh * 64 + e) * MM + mt * 64 + c;
    *(uint4*)dst = a;
    *(uint4*)(dst + 8) = b;
}

// ---------------- out (1 barrier/iter, direct store) ----------------
template <bool BF16>
__device__ void out_impl(const void* Q, const void* P, const float* cqw,
                         const unsigned short* kvT, const float* ksum, void* out,
                         unsigned short Qs[64][72], unsigned short Ps[2][64][72],
                         unsigned short KVs[2][64][72], unsigned short Fs[64][72],
                         unsigned short kss[2][72]) {
    const int t = threadIdx.x;
    const int w = t >> 6, ln = t & 15, quad = (t >> 4) & 3;
    const int lb = blockIdx.x, nh = blockIdx.y;
    const int n = nh >> 3, h = nh & 7;
    const size_t qbase = (size_t)n * (LL * ROWSTR) + (size_t)h * 64 + (size_t)(lb * 64) * ROWSTR;
    const size_t kvbase = (size_t)nh * (size_t)(64 * MM);

    {
        uint4 qa, qb;
        tile_load<BF16>(Q, qbase, ROWSTR, t, qa, qb);
        tile_store(Qs, t, qa, qb);
    }
    uint4 pA, pB, kA, kB;
    float ksr = 0.f;
    // iter 0 -> buf 0
    tile_load<BF16>(P, 0, 64, t, pA, pB);
    tile_load<true>(kvT, kvbase, MM, t, kA, kB);
    if (t < 64) ksr = ksum[(size_t)nh * MM + t];
    tile_store(Ps[0], t, pA, pB);
    tile_store(KVs[0], t, kA, kB);
    if (t < 64) kss[0][t] = f2bf(ksr);
    // prefetch iter 1
    tile_load<BF16>(P, (size_t)64 * 64, 64, t, pA, pB);
    tile_load<true>(kvT, kvbase + 64, MM, t, kA, kB);
    if (t < 64) ksr = ksum[(size_t)nh * MM + 64 + t];
    __syncthreads();

    const short8 qb0 = *(const short8*)&Qs[16 * w + ln][quad * 8];
    const short8 qb1 = *(const short8*)&Qs[16 * w + ln][32 + quad * 8];
    const float cq = cqw[(size_t)nh * LL + lb * 64 + 16 * w + ln];

    f32x4 ao[4] = {{0.f, 0.f, 0.f, 0.f}, {0.f, 0.f, 0.f, 0.f},
                   {0.f, 0.f, 0.f, 0.f}, {0.f, 0.f, 0.f, 0.f}};
    f32x4 ad = {0.f, 0.f, 0.f, 0.f};

    for (int mt = 0; mt < 32; ++mt) {
        const int cur = mt & 1;
        if (mt + 1 < 32) {
            tile_store(Ps[cur ^ 1], t, pA, pB);
            tile_store(KVs[cur ^ 1], t, kA, kB);
            if (t < 64) kss[cur ^ 1][t] = f2bf(ksr);
            if (mt + 2 < 32) {
                tile_load<BF16>(P, (size_t)((mt + 2) * 64) * 64, 64, t, pA, pB);
                tile_load<true>(kvT, kvbase + (mt + 2) * 64, MM, t, kA, kB);
                if (t < 64) ksr = ksum[(size_t)nh * MM + (mt + 2) * 64 + t];
            }
        }
        // gemm1 -> Fs (wave-local rows)
        #pragma unroll
        for (int ms = 0; ms < 4; ++ms) {
            f32x4 acc = {0.f, 0.f, 0.f, 0.f};
            acc = MFMA(*(const short8*)&Ps[cur][16 * ms + ln][quad * 8], qb0, acc);
            acc = MFMA(*(const short8*)&Ps[cur][16 * ms + ln][32 + quad * 8], qb1, acc);
            float f[4];
            #pragma unroll
            for (int j = 0; j < 4; ++j) {
                const float arg = fminf(fmaf(acc[j], NORMC, -cq), 0.f);
                f[j] = fmaf(__expf(arg), RATIO, REPS);
            }
            uint2 o; o.x = pk2(f[0], f[1]); o.y = pk2(f[2], f[3]);
            *(uint2*)&Fs[16 * w + ln][16 * ms + 4 * quad] = o;  // Fs[l][m]
        }
        // gemm2
        #pragma unroll
        for (int k = 0; k < 2; ++k) {
            const short8 af = *(const short8*)&Fs[16 * w + ln][32 * k + quad * 8];
            const short8 bs = *(const short8*)&kss[cur][32 * k + quad * 8];
            ad = MFMA(af, bs, ad);
            #pragma unroll
            for (int es = 0; es < 4; ++es)
                ao[es] = MFMA(af, *(const short8*)&KVs[cur][16 * es + ln][32 * k + quad * 8],
                              ao[es]);
        }
        __syncthreads();
    }
    float z[4];
    #pragma unroll
    for (int r = 0; r < 4; ++r) z[r] = 1.0f / (ad[r] + EPSD);
    #pragma unroll
    for (int r = 0; r < 4; ++r) {
        const int l = lb * 64 + 16 * w + 4 * quad + r;
        const size_t rowoff = ((size_t)(n * LL + l) * HH + h) * 64;
        #pragma unroll
        for (int es = 0; es < 4; ++es) {
            const float val = ao[es][r] * z[r];
            if (BF16) ((unsigned short*)out)[rowoff + 16 * es + ln] = f2bf(val);
            else ((float*)out)[rowoff + 16 * es + ln] = val;
        }
    }
}

__global__ __launch_bounds__(256) void LinearAttention_15985868276494_out(
        const void* Q, const void* P, const float* flag, const float* cqw,
        const unsigned short* kvT, const float* ksum, void* out) {
    __shared__ unsigned short Qs[64][72];
    __shared__ unsigned short Ps[2][64][72];
    __shared__ unsigned short KVs[2][64][72];
    __shared__ unsigned short Fs[64][72];
    __shared__ unsigned short kss[2][72];
    if (*flag != 0.f) out_impl<true>(Q, P, cqw, kvT, ksum, out, Qs, Ps, KVs, Fs, kss);
    else out_impl<false>(Q, P, cqw, kvT, ksum, out, Qs, Ps, KVs, Fs, kss);
}

extern "C" void kernel_launch(void* const* d_in, const int* in_sizes, int n_in,
                              void* d_out, int out_size, void* d_ws, size_t ws_size,
                              hipStream_t stream) {
    const void* Q = d_in[0];
    const void* K = d_in[1];
    const void* V = d_in[2];
    const void* P = d_in[3];

    float* W = (float*)d_ws;
    float* flag = W;                                  // [16]
    float* c_k = W + 16;                              // [32768]
    float* c_q = c_k + 32768;                         // [32768]
    float* ksum01 = c_q + 32768;                      // [2][32768]
    float* kvf01 = ksum01 + 2 * RSPLIT;               // [2][16][2048][64] f32
    float* ksumW = kvf01 + 2 * KVSPLIT;               // [32768]
    unsigned short* kvTW = (unsigned short*)(ksumW + RSPLIT);  // [16][64][2048] bf16

    LinearAttention_15985868276494_detect<<<1, 64, 0, stream>>>(
        (const unsigned short*)P, flag);
    LinearAttention_15985868276494_stats<<<dim3(512, 2), 256, 0, stream>>>(
        K, Q, P, flag, c_k, c_q);
    LinearAttention_15985868276494_kv<<<dim3(32, 16, 2), 256, 0, stream>>>(
        K, V, P, flag, c_k, kvf01, ksum01);
    LinearAttention_15985868276494_reduce<<<dim3(32, 16), 256, 0, stream>>>(
        kvf01, ksum01, kvTW, ksumW);
    LinearAttention_15985868276494_out<<<dim3(32, 16), 256, 0, stream>>>(
        Q, P, flag, c_q, kvTW, ksumW, d_out);
}

// Round 7
// 191.462 us; speedup vs baseline: 1.3487x; 1.1206x over previous
//
#include <hip/hip_runtime.h>

// Performer linear attention, 32x32x16 MFMA, register-resident features.
// n=2, l=2048, h=8, e=64, m=2048. Dtype runtime-detected (bf16 confirmed R3-R6).
// ws (floats): flag[16] | c_k[32768] | c_q[32768] | ksum01[2][32768]
//   | kvf01[2][16][64][2048] f32 (e-major) | ksumW[32768] | kvT bf16[16][64][2048]

#define LL 2048
#define HH 8
#define MM 2048
#define ROWSTR 512  // HH*64

#define NORMC 0.35355339059327373f   // 64^-0.25
#define RATIO 0.022097086912079608f  // 2048^-0.5
#define KEPS 1e-4f
#define REPS (RATIO * KEPS)
#define EPSD 1e-6f

#define KVSPLIT 2097152
#define RSPLIT 32768

typedef __attribute__((ext_vector_type(8))) short short8;
typedef __attribute__((ext_vector_type(16))) float f32x16;

#define MFMA32(a, b, c) __builtin_amdgcn_mfma_f32_32x32x16_bf16((a), (b), (c), 0, 0, 0)

__device__ __forceinline__ f32x16 zero16() {
    f32x16 v;
    #pragma unroll
    for (int i = 0; i < 16; ++i) v[i] = 0.f;
    return v;
}
__device__ __forceinline__ unsigned short f2bf(float f) {  // RNE
    union { float f; unsigned int u; } v; v.f = f;
    unsigned int r = v.u + 0x7fffu + ((v.u >> 16) & 1u);
    return (unsigned short)(r >> 16);
}
__device__ __forceinline__ unsigned int pk2(float lo, float hi) {  // trunc pack
    return __builtin_amdgcn_perm(__float_as_uint(hi), __float_as_uint(lo), 0x07060302u);
}
__device__ __forceinline__ float bf2f(unsigned short u) {
    union { unsigned int ui; float f; } v; v.ui = ((unsigned int)u) << 16; return v.f;
}

// ---- 64x64 tile staging into LDS [64][72] bf16 ----
template <bool BF16>
__device__ __forceinline__ void tile_load(const void* src, size_t base, size_t rstride,
                                          int t, uint4& A, uint4& B) {
    const int row = t >> 2, c16 = (t & 3) * 16;
    if (BF16) {
        const unsigned short* p = (const unsigned short*)src + base + (size_t)row * rstride + c16;
        A = *(const uint4*)p;
        B = *(const uint4*)(p + 8);
    } else {
        const float* p = (const float*)src + base + (size_t)row * rstride + c16;
        float4 f0 = ((const float4*)p)[0], f1 = ((const float4*)p)[1];
        float4 f2 = ((const float4*)p)[2], f3 = ((const float4*)p)[3];
        A.x = pk2(f0.x, f0.y); A.y = pk2(f0.z, f0.w);
        A.z = pk2(f1.x, f1.y); A.w = pk2(f1.z, f1.w);
        B.x = pk2(f2.x, f2.y); B.y = pk2(f2.z, f2.w);
        B.z = pk2(f3.x, f3.y); B.w = pk2(f3.z, f3.w);
    }
}
__device__ __forceinline__ void tile_store72(unsigned short* D, int t, uint4 A, uint4 B) {
    const int row = t >> 2, c16 = (t & 3) * 16;
    *(uint4*)&D[row * 72 + c16] = A;
    *(uint4*)&D[row * 72 + c16 + 8] = B;
}

// ---- V transpose staging into LDS [64e][72] ----
template <bool BF16>
__device__ __forceinline__ void vt_load(const void* V, size_t base, int t, uint4& A, uint4& B) {
    const int s0 = (t & 31) * 2, e0 = (t >> 5) * 8;
    if (BF16) {
        const unsigned short* p = (const unsigned short*)V + base + (size_t)s0 * ROWSTR + e0;
        A = *(const uint4*)p;
        B = *(const uint4*)(p + ROWSTR);
    } else {
        const float* p = (const float*)V + base + (size_t)s0 * ROWSTR + e0;
        float4 f0 = ((const float4*)p)[0], f1 = ((const float4*)p)[1];
        const float* q = p + ROWSTR;
        float4 g0 = ((const float4*)q)[0], g1 = ((const float4*)q)[1];
        A.x = pk2(f0.x, f0.y); A.y = pk2(f0.z, f0.w);
        A.z = pk2(f1.x, f1.y); A.w = pk2(f1.z, f1.w);
        B.x = pk2(g0.x, g0.y); B.y = pk2(g0.z, g0.w);
        B.z = pk2(g1.x, g1.y); B.w = pk2(g1.z, g1.w);
    }
}
__device__ __forceinline__ void vt_store72(unsigned short* VT, int t, uint4 A, uint4 B) {
    const int s0 = (t & 31) * 2, e0 = (t >> 5) * 8;
    const unsigned ua[4] = {A.x, A.y, A.z, A.w}, ub[4] = {B.x, B.y, B.z, B.w};
    #pragma unroll
    for (int i = 0; i < 4; ++i) {
        *(unsigned*)&VT[(e0 + 2 * i) * 72 + s0] = (ua[i] & 0xFFFFu) | (ub[i] << 16);
        *(unsigned*)&VT[(e0 + 2 * i + 1) * 72 + s0] = (ua[i] >> 16) | (ub[i] & 0xFFFF0000u);
    }
}

// ---- D-layout -> B-operand exchange (half-wave) ----
// B-frag(chunk cp): j0-3 from lane-half 0 regs (b+8cp+4hi_tgt), j4-7 from half 1.
__device__ __forceinline__ short8 xfrag(const unsigned int pd[8], int cp, int hi) {
    const unsigned int s0 = hi ? pd[4 * cp + 0] : pd[4 * cp + 2];
    const unsigned int s1 = hi ? pd[4 * cp + 1] : pd[4 * cp + 3];
    const unsigned int r0 = (unsigned int)__shfl_xor((int)s0, 32);
    const unsigned int r1 = (unsigned int)__shfl_xor((int)s1, 32);
    union { unsigned int u[4]; short8 s; } v;
    v.u[0] = hi ? r0 : pd[4 * cp + 0];
    v.u[1] = hi ? r1 : pd[4 * cp + 1];
    v.u[2] = hi ? pd[4 * cp + 2] : r0;
    v.u[3] = hi ? pd[4 * cp + 3] : r1;
    return v.s;
}

// ---------------- dtype detection ----------------
__global__ void LinearAttention_15985868276494_detect(const unsigned short* __restrict__ P,
                                                      float* __restrict__ flag) {
    if (threadIdx.x == 0) {
        int sane = 1;
        #pragma unroll
        for (int i = 0; i < 16; ++i) {
            const unsigned e = (P[2 * i] >> 7) & 0xFF;
            if (e < 101 || e > 141) sane = 0;
        }
        *flag = sane ? 1.0f : 0.0f;
    }
}

// ---------------- stats: c[nh][l], 128 rows x 128-m tiles ----------------
template <bool BF16>
__device__ void stats_impl(const void* X, const void* P, float* cws,
                           unsigned short* Xs, unsigned short* Ps, float* red) {
    const int t = threadIdx.x;
    const int w = t >> 6, ln = t & 31, hi = (t >> 5) & 1;
    const int row_base = blockIdx.x * 128;

    uint4 a0, b0, a1, b1;
    tile_load<BF16>(X, (size_t)row_base * 64, 64, t, a0, b0);
    tile_store72(Xs, t, a0, b0);
    tile_load<BF16>(X, (size_t)(row_base + 64) * 64, 64, t, a1, b1);
    tile_store72(Xs + 64 * 72, t, a1, b1);
    tile_load<BF16>(P, 0, 64, t, a0, b0);
    tile_store72(Ps, t, a0, b0);
    tile_load<BF16>(P, (size_t)64 * 64, 64, t, a1, b1);
    tile_store72(Ps + 64 * 72, t, a1, b1);
    uint4 pA0, pB0, pA1, pB1;
    tile_load<BF16>(P, (size_t)128 * 64, 64, t, pA0, pB0);
    tile_load<BF16>(P, (size_t)192 * 64, 64, t, pA1, pB1);
    __syncthreads();

    short8 xb[4][4];
    #pragma unroll
    for (int xs = 0; xs < 4; ++xs)
        #pragma unroll
        for (int c = 0; c < 4; ++c)
            xb[xs][c] = *(const short8*)&Xs[(32 * xs + ln) * 72 + 16 * c + 8 * hi];

    float rmax4[4] = {-3e38f, -3e38f, -3e38f, -3e38f};
    for (int mt = 0; mt < 16; ++mt) {
        const int cur = mt & 1;
        unsigned short* Pc = Ps + cur * (128 * 72);
        if (mt + 1 < 16) {
            unsigned short* Pn = Ps + (cur ^ 1) * (128 * 72);
            tile_store72(Pn, t, pA0, pB0);
            tile_store72(Pn + 64 * 72, t, pA1, pB1);
            if (mt + 2 < 16) {
                tile_load<BF16>(P, (size_t)((mt + 2) * 128) * 64, 64, t, pA0, pB0);
                tile_load<BF16>(P, (size_t)((mt + 2) * 128 + 64) * 64, 64, t, pA1, pB1);
            }
        }
        #pragma unroll
        for (int xs = 0; xs < 4; ++xs) {
            f32x16 acc = zero16();
            #pragma unroll
            for (int c = 0; c < 4; ++c) {
                const short8 af = *(const short8*)&Pc[(32 * w + ln) * 72 + 16 * c + 8 * hi];
                acc = MFMA32(af, xb[xs][c], acc);
            }
            float m = acc[0];
            #pragma unroll
            for (int r = 1; r < 16; ++r) m = fmaxf(m, acc[r]);
            rmax4[xs] = fmaxf(rmax4[xs], m);
        }
        __syncthreads();
    }
    #pragma unroll
    for (int xs = 0; xs < 4; ++xs) {
        const float m = fmaxf(rmax4[xs], __shfl_xor(rmax4[xs], 32));
        if (hi == 0) red[w * 128 + xs * 32 + ln] = m;
    }
    __syncthreads();
    if (t < 128) {
        const float rm = fmaxf(fmaxf(red[t], red[128 + t]), fmaxf(red[256 + t], red[384 + t]));
        float s2 = 0.f;
        #pragma unroll
        for (int c = 0; c < 64; c += 8) {
            uint4 u = *(const uint4*)&Xs[t * 72 + c];
            const unsigned int ua[4] = {u.x, u.y, u.z, u.w};
            #pragma unroll
            for (int i = 0; i < 4; ++i) {
                const float lo = bf2f((unsigned short)(ua[i] & 0xFFFF));
                const float hv = bf2f((unsigned short)(ua[i] >> 16));
                s2 = fmaf(lo, lo, s2); s2 = fmaf(hv, hv, s2);
            }
        }
        const int rg = row_base + t;
        const int n = rg >> 14, l = (rg >> 3) & 2047, h = rg & 7;
        cws[(size_t)((n << 3) | h) * LL + l] = NORMC * rm + (0.5f * NORMC * NORMC) * s2;
    }
}

__global__ __launch_bounds__(256, 2) void LinearAttention_15985868276494_stats(
        const void* K, const void* Q, const void* P, const float* flag,
        float* c_k, float* c_q) {
    __shared__ unsigned short Xs[128 * 72];
    __shared__ unsigned short Ps[2 * 128 * 72];
    __shared__ float red[512];
    const void* X = (blockIdx.y == 0) ? K : Q;
    float* cws = (blockIdx.y == 0) ? c_k : c_q;
    if (*flag != 0.f) stats_impl<true>(X, P, cws, Xs, Ps, red);
    else stats_impl<false>(X, P, cws, Xs, Ps, red);
}

// ---------------- kv: partial kvf[sp][nh][e][m] f32, ksum01 ----------------
template <bool BF16>
__device__ void kv_impl(const void* K, const void* V, const void* P, const float* cws,
                        float* kvf01, float* ksum01, char* smem) {
    unsigned short* Ks = (unsigned short*)smem;            // [2][64*72]
    unsigned short* VT = (unsigned short*)(smem + 18432);  // [2][64*72]
    unsigned short* Ps = (unsigned short*)(smem + 36864);  // [64*72]
    float* cks = (float*)(smem + 46080);                   // [2][64]
    float* fin = (float*)smem;                             // [4*64*36], aliases Ks+VT

    const int t = threadIdx.x;
    const int w = t >> 6, ln = t & 31, hi = (t >> 5) & 1;
    const int sstrip = w & 1, mstrip = w >> 1;
    const int mt = blockIdx.x, nh = blockIdx.y, sp = blockIdx.z;
    const int n = nh >> 3, h = nh & 7;
    const size_t xbase = (size_t)n * (LL * ROWSTR) + (size_t)h * 64;
    const int st0 = sp * 16;

    {
        uint4 pa, pbv;
        tile_load<BF16>(P, (size_t)(mt * 64) * 64, 64, t, pa, pbv);
        tile_store72(Ps, t, pa, pbv);
    }
    uint4 kA, kB, vA, vB; float ckr = 0.f;
    tile_load<BF16>(K, xbase + (size_t)(st0 * 64) * ROWSTR, ROWSTR, t, kA, kB);
    vt_load<BF16>(V, xbase + (size_t)(st0 * 64) * ROWSTR, t, vA, vB);
    if (t < 64) ckr = cws[(size_t)nh * LL + st0 * 64 + t];
    tile_store72(Ks, t, kA, kB);
    vt_store72(VT, t, vA, vB);
    if (t < 64) cks[t] = ckr;
    tile_load<BF16>(K, xbase + (size_t)((st0 + 1) * 64) * ROWSTR, ROWSTR, t, kA, kB);
    vt_load<BF16>(V, xbase + (size_t)((st0 + 1) * 64) * ROWSTR, t, vA, vB);
    if (t < 64) ckr = cws[(size_t)nh * LL + (st0 + 1) * 64 + t];
    __syncthreads();

    short8 pb[4];
    #pragma unroll
    for (int c = 0; c < 4; ++c)
        pb[c] = *(const short8*)&Ps[(32 * mstrip + ln) * 72 + 16 * c + 8 * hi];
    const short8 ones = {0x3F80, 0x3F80, 0x3F80, 0x3F80, 0x3F80, 0x3F80, 0x3F80, 0x3F80};

    f32x16 akv0 = zero16(), akv1 = zero16(), aks = zero16();

    for (int i = 0; i < 16; ++i) {
        const int cur = i & 1;
        unsigned short* Kc = Ks + cur * 4608;
        unsigned short* Vc = VT + cur * 4608;
        const float* cc = cks + cur * 64;
        if (i + 1 < 16) {
            tile_store72(Ks + (cur ^ 1) * 4608, t, kA, kB);
            vt_store72(VT + (cur ^ 1) * 4608, t, vA, vB);
            if (t < 64) cks[(cur ^ 1) * 64 + t] = ckr;
            if (i + 2 < 16) {
                const int st = st0 + i + 2;
                tile_load<BF16>(K, xbase + (size_t)(st * 64) * ROWSTR, ROWSTR, t, kA, kB);
                vt_load<BF16>(V, xbase + (size_t)(st * 64) * ROWSTR, t, vA, vB);
                if (t < 64) ckr = cws[(size_t)nh * LL + st * 64 + t];
            }
        }
        // gemm1: D[s][m] = K . P^T  (col=lane&31=m)
        f32x16 D = zero16();
        #pragma unroll
        for (int c = 0; c < 4; ++c) {
            const short8 af = *(const short8*)&Kc[(32 * sstrip + ln) * 72 + 16 * c + 8 * hi];
            D = MFMA32(af, pb[c], D);
        }
        // exp (c varies with s = row)
        unsigned int pd[8];
        #pragma unroll
        for (int g = 0; g < 4; ++g) {
            const float4 c4 = *(const float4*)&cc[32 * sstrip + 8 * g + 4 * hi];
            const float ca[4] = {c4.x, c4.y, c4.z, c4.w};
            float f[4];
            #pragma unroll
            for (int b = 0; b < 4; ++b) {
                const float arg = fminf(fmaf(D[4 * g + b], NORMC, -ca[b]), 0.f);
                f[b] = fmaf(__expf(arg), RATIO, REPS);
            }
            pd[2 * g] = pk2(f[0], f[1]);
            pd[2 * g + 1] = pk2(f[2], f[3]);
        }
        // gemm2: akv[e][m] += V^T . F   (register F via exchange)
        #pragma unroll
        for (int cp = 0; cp < 2; ++cp) {
            const short8 bf = xfrag(pd, cp, hi);
            const int scol = 32 * sstrip + 16 * cp + 8 * hi;
            const short8 v0 = *(const short8*)&Vc[ln * 72 + scol];
            const short8 v1 = *(const short8*)&Vc[(32 + ln) * 72 + scol];
            akv0 = MFMA32(v0, bf, akv0);
            akv1 = MFMA32(v1, bf, akv1);
            aks = MFMA32(ones, bf, aks);
        }
        __syncthreads();
    }
    // cross-sstrip reduce + store
    {
        const int slot = (w * 64 + (t & 63)) * 36;
        #pragma unroll
        for (int r = 0; r < 16; ++r) fin[slot + r] = akv0[r];
        #pragma unroll
        for (int r = 0; r < 16; ++r) fin[slot + 16 + r] = akv1[r];
        fin[slot + 32] = aks[0];
    }
    __syncthreads();
    {
        const int e = t >> 2;
        const int t16 = e >> 5, e5 = e & 31;
        const int hi_s = (e5 >> 2) & 1;
        const int reg = 16 * t16 + (e5 & 3) + 4 * (e5 >> 3);
        float* dst = kvf01 + (size_t)sp * KVSPLIT + (size_t)nh * (64 * MM)
                   + (size_t)e * MM + mt * 64 + (t & 3) * 16;
        #pragma unroll
        for (int jq = 0; jq < 4; ++jq) {
            float o[4];
            #pragma unroll
            for (int b = 0; b < 4; ++b) {
                const int m_local = (t & 3) * 16 + 4 * jq + b;
                const int ms = m_local >> 5;
                const int lane_s = hi_s * 32 + (m_local & 31);
                o[b] = fin[((2 * ms) * 64 + lane_s) * 36 + reg]
                     + fin[((2 * ms + 1) * 64 + lane_s) * 36 + reg];
            }
            *(float4*)&dst[4 * jq] = make_float4(o[0], o[1], o[2], o[3]);
        }
        if (t < 64) {
            const int ms = t >> 5;
            const float val = fin[((2 * ms) * 64 + (t & 31)) * 36 + 32]
                            + fin[((2 * ms + 1) * 64 + (t & 31)) * 36 + 32];
            ksum01[(size_t)sp * RSPLIT + (size_t)nh * MM + mt * 64 + t] = val;
        }
    }
}

__global__ __launch_bounds__(256, 3) void LinearAttention_15985868276494_kv(
        const void* K, const void* V, const void* P, const float* flag,
        const float* cws, float* kvf01, float* ksum01) {
    extern __shared__ char smem_kv[];
    if (*flag != 0.f) kv_impl<true>(K, V, P, cws, kvf01, ksum01, smem_kv);
    else kv_impl<false>(K, V, P, cws, kvf01, ksum01, smem_kv);
}

// ---------------- reduce: kvT bf16 = split0+split1 (element-wise); ksumW ----------------
__global__ __launch_bounds__(256) void LinearAttention_15985868276494_reduce(
        const float* __restrict__ kvf01, const float* __restrict__ ksum01,
        unsigned short* __restrict__ kvT, float* __restrict__ ksumW) {
    const int gid = blockIdx.x * 256 + threadIdx.x;
    const size_t i4 = (size_t)gid * 4;
    const float4 a = *(const float4*)&kvf01[i4];
    const float4 b = *(const float4*)&kvf01[KVSPLIT + i4];
    uint2 o;
    o.x = (unsigned)f2bf(a.x + b.x) | ((unsigned)f2bf(a.y + b.y) << 16);
    o.y = (unsigned)f2bf(a.z + b.z) | ((unsigned)f2bf(a.w + b.w) << 16);
    *(uint2*)&kvT[i4] = o;
    if (blockIdx.x < 32) {
        const float4 c = *(const float4*)&ksum01[i4];
        const float4 d = *(const float4*)&ksum01[RSPLIT + i4];
        *(float4*)&ksumW[i4] = make_float4(c.x + d.x, c.y + d.y, c.z + d.z, c.w + d.w);
    }
}

// ---------------- out ----------------
template <bool BF16>
__device__ void out_impl(const void* Q, const void* P, const float* cqw,
                         const unsigned short* kvT, const float* ksum, void* outp,
                         char* smem) {
    unsigned short* Qs = (unsigned short*)smem;              // 64*72
    unsigned short* Ps = (unsigned short*)(smem + 9216);     // [2][64*72]
    unsigned short* KVs = (unsigned short*)(smem + 27648);   // [2][64*72]
    unsigned short* kss = (unsigned short*)(smem + 46080);   // [2][64]
    float* fin = (float*)(smem + 9216);                      // [4*64*36], aliases Ps+KVs

    const int t = threadIdx.x;
    const int w = t >> 6, ln = t & 31, hi = (t >> 5) & 1;
    const int mstrip = w & 1, lstrip = w >> 1;
    const int lb = blockIdx.x, nh = blockIdx.y;
    const int n = nh >> 3, h = nh & 7;
    const size_t qbase = (size_t)n * (LL * ROWSTR) + (size_t)h * 64 + (size_t)(lb * 64) * ROWSTR;
    const size_t kvbase = (size_t)nh * (size_t)(64 * MM);

    {
        uint4 qa, qbv;
        tile_load<BF16>(Q, qbase, ROWSTR, t, qa, qbv);
        tile_store72(Qs, t, qa, qbv);
    }
    uint4 pA, pB, kA, kB; float ksr = 0.f;
    tile_load<BF16>(P, 0, 64, t, pA, pB);
    tile_load<true>(kvT, kvbase, MM, t, kA, kB);
    if (t < 64) ksr = ksum[(size_t)nh * MM + t];
    tile_store72(Ps, t, pA, pB);
    tile_store72(KVs, t, kA, kB);
    if (t < 64) kss[t] = f2bf(ksr);
    tile_load<BF16>(P, (size_t)64 * 64, 64, t, pA, pB);
    tile_load<true>(kvT, kvbase + 64, MM, t, kA, kB);
    if (t < 64) ksr = ksum[(size_t)nh * MM + 64 + t];
    __syncthreads();

    short8 qb[4];
    #pragma unroll
    for (int c = 0; c < 4; ++c)
        qb[c] = *(const short8*)&Qs[(32 * lstrip + ln) * 72 + 16 * c + 8 * hi];
    const float cq = cqw[(size_t)nh * LL + lb * 64 + lstrip * 32 + ln];

    f32x16 ao0 = zero16(), ao1 = zero16(), ad = zero16();

    for (int mt = 0; mt < 32; ++mt) {
        const int cur = mt & 1;
        unsigned short* Pc = Ps + cur * 4608;
        unsigned short* Kc = KVs + cur * 4608;
        const unsigned short* ksc = kss + cur * 64;
        if (mt + 1 < 32) {
            tile_store72(Ps + (cur ^ 1) * 4608, t, pA, pB);
            tile_store72(KVs + (cur ^ 1) * 4608, t, kA, kB);
            if (t < 64) kss[(cur ^ 1) * 64 + t] = f2bf(ksr);
            if (mt + 2 < 32) {
                tile_load<BF16>(P, (size_t)((mt + 2) * 64) * 64, 64, t, pA, pB);
                tile_load<true>(kvT, kvbase + (mt + 2) * 64, MM, t, kA, kB);
                if (t < 64) ksr = ksum[(size_t)nh * MM + (mt + 2) * 64 + t];
            }
        }
        // gemm1: D[m][l] = P . Q^T  (col=lane&31=l)
        f32x16 D = zero16();
        #pragma unroll
        for (int c = 0; c < 4; ++c) {
            const short8 af = *(const short8*)&Pc[(32 * mstrip + ln) * 72 + 16 * c + 8 * hi];
            D = MFMA32(af, qb[c], D);
        }
        // exp (c depends on l = col only)
        unsigned int pd[8];
        #pragma unroll
        for (int g = 0; g < 4; ++g) {
            float f[4];
            #pragma unroll
            for (int b = 0; b < 4; ++b) {
                const float arg = fminf(fmaf(D[4 * g + b], NORMC, -cq), 0.f);
                f[b] = fmaf(__expf(arg), RATIO, REPS);
            }
            pd[2 * g] = pk2(f[0], f[1]);
            pd[2 * g + 1] = pk2(f[2], f[3]);
        }
        // gemm2: O[e][l] += KV . F ; ad[.][l] += ksum . F
        #pragma unroll
        for (int cp = 0; cp < 2; ++cp) {
            const short8 bf = xfrag(pd, cp, hi);
            const int mcol = 32 * mstrip + 16 * cp + 8 * hi;
            const short8 a0 = *(const short8*)&Kc[ln * 72 + mcol];
            const short8 a1 = *(const short8*)&Kc[(32 + ln) * 72 + mcol];
            const short8 k8 = *(const short8*)&ksc[mcol];
            ao0 = MFMA32(a0, bf, ao0);
            ao1 = MFMA32(a1, bf, ao1);
            ad = MFMA32(k8, bf, ad);
        }
        __syncthreads();
    }
    {
        const int slot = (w * 64 + (t & 63)) * 36;
        #pragma unroll
        for (int r = 0; r < 16; ++r) fin[slot + r] = ao0[r];
        #pragma unroll
        for (int r = 0; r < 16; ++r) fin[slot + 16 + r] = ao1[r];
        fin[slot + 32] = ad[0];
    }
    __syncthreads();
    {
        const int l_local = t >> 2, eg = t & 3;
        const int ls = l_local >> 5, lane_l = l_local & 31;
        const float adt = fin[((2 * ls) * 64 + lane_l) * 36 + 32]
                        + fin[((2 * ls + 1) * 64 + lane_l) * 36 + 32];
        const float z = 1.0f / (adt + EPSD);
        const int l = lb * 64 + l_local;
        const size_t rowoff = ((size_t)(n * LL + l) * HH + h) * 64 + eg * 16;
        float vals[16];
        #pragma unroll
        for (int j = 0; j < 16; ++j) {
            const int e = eg * 16 + j;
            const int t16 = e >> 5, e5 = e & 31;
            const int hi_s = (e5 >> 2) & 1;
            const int reg = 16 * t16 + (e5 & 3) + 4 * (e5 >> 3);
            const int lane_s = hi_s * 32 + lane_l;
            vals[j] = (fin[((2 * ls) * 64 + lane_s) * 36 + reg]
                     + fin[((2 * ls + 1) * 64 + lane_s) * 36 + reg]) * z;
        }
        if (BF16) {
            uint4 o0, o1;
            o0.x = (unsigned)f2bf(vals[0]) | ((unsigned)f2bf(vals[1]) << 16);
            o0.y = (unsigned)f2bf(vals[2]) | ((unsigned)f2bf(vals[3]) << 16);
            o0.z = (unsigned)f2bf(vals[4]) | ((unsigned)f2bf(vals[5]) << 16);
            o0.w = (unsigned)f2bf(vals[6]) | ((unsigned)f2bf(vals[7]) << 16);
            o1.x = (unsigned)f2bf(vals[8]) | ((unsigned)f2bf(vals[9]) << 16);
            o1.y = (unsigned)f2bf(vals[10]) | ((unsigned)f2bf(vals[11]) << 16);
            o1.z = (unsigned)f2bf(vals[12]) | ((unsigned)f2bf(vals[13]) << 16);
            o1.w = (unsigned)f2bf(vals[14]) | ((unsigned)f2bf(vals[15]) << 16);
            unsigned short* op = (unsigned short*)outp + rowoff;
            *(uint4*)op = o0;
            *(uint4*)(op + 8) = o1;
        } else {
            float* op = (float*)outp + rowoff;
            #pragma unroll
            for (int q4 = 0; q4 < 4; ++q4)
                *(float4*)&op[4 * q4] = make_float4(vals[4 * q4], vals[4 * q4 + 1],
                                                    vals[4 * q4 + 2], vals[4 * q4 + 3]);
        }
    }
}

__global__ __launch_bounds__(256, 3) void LinearAttention_15985868276494_out(
        const void* Q, const void* P, const float* flag, const float* cqw,
        const unsigned short* kvT, const float* ksum, void* outp) {
    extern __shared__ char smem_out[];
    if (*flag != 0.f) out_impl<true>(Q, P, cqw, kvT, ksum, outp, smem_out);
    else out_impl<false>(Q, P, cqw, kvT, ksum, outp, smem_out);
}

extern "C" void kernel_launch(void* const* d_in, const int* in_sizes, int n_in,
                              void* d_out, int out_size, void* d_ws, size_t ws_size,
                              hipStream_t stream) {
    const void* Q = d_in[0];
    const void* K = d_in[1];
    const void* V = d_in[2];
    const void* P = d_in[3];

    float* W = (float*)d_ws;
    float* flag = W;                                  // [16]
    float* c_k = W + 16;                              // [32768]
    float* c_q = c_k + 32768;                         // [32768]
    float* ksum01 = c_q + 32768;                      // [2][32768]
    float* kvf01 = ksum01 + 2 * RSPLIT;               // [2][16][64][2048] f32
    float* ksumW = kvf01 + 2 * KVSPLIT;               // [32768]
    unsigned short* kvTW = (unsigned short*)(ksumW + RSPLIT);  // [16][64][2048] bf16

    LinearAttention_15985868276494_detect<<<1, 64, 0, stream>>>(
        (const unsigned short*)P, flag);
    LinearAttention_15985868276494_stats<<<dim3(256, 2), 256, 0, stream>>>(
        K, Q, P, flag, c_k, c_q);
    LinearAttention_15985868276494_kv<<<dim3(32, 16, 2), 256, 46592, stream>>>(
        K, V, P, flag, c_k, kvf01, ksum01);
    LinearAttention_15985868276494_reduce<<<2048, 256, 0, stream>>>(
        kvf01, ksum01, kvTW, ksumW);
    LinearAttention_15985868276494_out<<<dim3(32, 16), 256, 46592, stream>>>(
        Q, P, flag, c_q, kvTW, ksumW, d_out);
}